// Round 21
// baseline (54.994 us; speedup 1.0000x reference)
//
#include <hip/hip_runtime.h>
#include <stdint.h>

#define BATCH 16
#define NPTS  4096
#define TOT   (BATCH * NPTS)     // 65536 points per tensor
#define JSEG  8

typedef float f4 __attribute__((ext_vector_type(4)));
typedef float f32x16 __attribute__((ext_vector_type(16)));
typedef short bh8 __attribute__((ext_vector_type(8)));   // 8 bf16 = 4 VGPR
typedef uint32_t u32;
typedef unsigned short u16;

__device__ __forceinline__ u16 bfr(float f) {
    union { float f; u32 u; } v; v.f = f;
    u32 r = v.u + 0x7FFF + ((v.u >> 16) & 1);
    return (u16)(r >> 16);
}
__device__ __forceinline__ float bfback(u16 h) {
    union { u32 u; float f; } v; v.u = ((u32)h) << 16; return v.f;
}
#define BF16_ONE ((u16)0x3F80)

#define MIN3r(d, a, b, c) \
    asm("v_min3_f32 %0, %1, %2, %3" : "=v"(d) : "v"(a), "v"(b), "v"(c))

// Record layout (verified R14; now K=16 exactly = 32x32x16's K):
//  A: [ahx,ahy,ahz, ahx,ahy,ahz, alx,aly | alz, x2h,x2l, 1,1, 0,0,0]   (A=-2x)
//  B: [yhx,yhy,yhz, ylx,yly,ylz, yhx,yhy | yhz, 1,1, y2h,y2l, 0,0,0]
// => sum_k A_k*B_k = Ah.Yh + Ah.Yl + Al.Yh + x2 + y2 == D[i,j]

__device__ __forceinline__ void build_arec(float a, float b, float c,
                                           bh8* h0, bh8* h1) {
    float s2 = fmaf(a, a, fmaf(b, b, c * c));
    u16 s2h = bfr(s2);
    u16 s2l = bfr(s2 - bfback(s2h));
    float ax = -2.0f * a, ay = -2.0f * b, az = -2.0f * c;
    u16 ahx = bfr(ax), ahy = bfr(ay), ahz = bfr(az);
    u16 alx = bfr(ax - bfback(ahx));
    u16 aly = bfr(ay - bfback(ahy));
    u16 alz = bfr(az - bfback(ahz));
    union { u16 h[8]; bh8 v; } r0, r1;
    r0.h[0] = ahx; r0.h[1] = ahy; r0.h[2] = ahz;
    r0.h[3] = ahx; r0.h[4] = ahy; r0.h[5] = ahz;
    r0.h[6] = alx; r0.h[7] = aly;
    r1.h[0] = alz; r1.h[1] = s2h; r1.h[2] = s2l;
    r1.h[3] = BF16_ONE; r1.h[4] = BF16_ONE;
    r1.h[5] = 0; r1.h[6] = 0; r1.h[7] = 0;
    *h0 = r0.v; *h1 = r1.v;
}

__device__ __forceinline__ void build_brec(float a, float b, float c,
                                           f4* v0, f4* v1) {
    float s2 = fmaf(a, a, fmaf(b, b, c * c));
    u16 s2h = bfr(s2);
    u16 s2l = bfr(s2 - bfback(s2h));
    u16 yhx = bfr(a), yhy = bfr(b), yhz = bfr(c);
    u16 ylx = bfr(a - bfback(yhx));
    u16 yly = bfr(b - bfback(yhy));
    u16 ylz = bfr(c - bfback(yhz));
    union { u16 h[16]; f4 v[2]; } rec;
    rec.h[0] = yhx;  rec.h[1] = yhy;  rec.h[2] = yhz;
    rec.h[3] = ylx;  rec.h[4] = yly;  rec.h[5] = ylz;
    rec.h[6] = yhx;  rec.h[7] = yhy;
    rec.h[8] = yhz;  rec.h[9] = BF16_ONE; rec.h[10] = BF16_ONE;
    rec.h[11] = s2h; rec.h[12] = s2l;
    rec.h[13] = 0; rec.h[14] = 0; rec.h[15] = 0;
    *v0 = rec.v[0]; *v1 = rec.v[1];
}

#define DSRL(dst, base, imm) \
    asm volatile("ds_read_b128 %0, %1 offset:" imm : "=v"(dst) : "v"(base))

#define WAITL(cnt, slot) do { \
    asm volatile("s_waitcnt lgkmcnt(" cnt ")" : "+v"(slot)); \
    __builtin_amdgcn_sched_barrier(0); \
} while (0)

// fold 16 accumulator elements (static indices)
#define FOLD16(ra, p) do { \
    ra[0]=fminf(ra[0],p[0]);   ra[1]=fminf(ra[1],p[1]); \
    ra[2]=fminf(ra[2],p[2]);   ra[3]=fminf(ra[3],p[3]); \
    ra[4]=fminf(ra[4],p[4]);   ra[5]=fminf(ra[5],p[5]); \
    ra[6]=fminf(ra[6],p[6]);   ra[7]=fminf(ra[7],p[7]); \
    ra[8]=fminf(ra[8],p[8]);   ra[9]=fminf(ra[9],p[9]); \
    ra[10]=fminf(ra[10],p[10]); ra[11]=fminf(ra[11],p[11]); \
    ra[12]=fminf(ra[12],p[12]); ra[13]=fminf(ra[13],p[13]); \
    ra[14]=fminf(ra[14],p[14]); ra[15]=fminf(ra[15],p[15]); \
} while (0)

// min of 16 values -> m (5+2 min3 + 1 fmin)
#define TREE16(m, p) do { \
    float t0,t1,t2,t3,t4,u0,u1; \
    MIN3r(t0, p[0], p[1], p[2]); \
    MIN3r(t1, p[3], p[4], p[5]); \
    MIN3r(t2, p[6], p[7], p[8]); \
    MIN3r(t3, p[9], p[10], p[11]); \
    MIN3r(t4, p[12], p[13], p[14]); \
    MIN3r(u0, t0, t1, t2); \
    MIN3r(u1, t3, t4, p[15]); \
    m = fminf(u0, u1); \
} while (0)

// one 32-col B-tile: 2 MFMA (64 rows), prefetch, fold+colmin+ds_min
#define TILE(slot, pfbase, pfimm) do { \
    WAITL_CUR(slot); \
    p = __builtin_amdgcn_mfma_f32_32x32x16_bf16(af0, slot, zc, 0, 0, 0); \
    q = __builtin_amdgcn_mfma_f32_32x32x16_bf16(af1, slot, zc, 0, 0, 0); \
    DSRL(slot, pfbase, pfimm); \
    float m0, m1, cv; \
    FOLD16(ra0, p); TREE16(m0, p); \
    FOLD16(ra1, q); TREE16(m1, q); \
    cv = fminf(m0, m1); \
    asm volatile("ds_min_f32 %0, %1" :: "v"(cma), "v"(cv)); \
    cma += 128; \
} while (0)

#define TILED(slot) do { \
    WAITL_CUR(slot); \
    p = __builtin_amdgcn_mfma_f32_32x32x16_bf16(af0, slot, zc, 0, 0, 0); \
    q = __builtin_amdgcn_mfma_f32_32x32x16_bf16(af1, slot, zc, 0, 0, 0); \
    float m0, m1, cv; \
    FOLD16(ra0, p); TREE16(m0, p); \
    FOLD16(ra1, q); TREE16(m1, q); \
    cv = fminf(m0, m1); \
    asm volatile("ds_min_f32 %0, %1" :: "v"(cma), "v"(cv)); \
    cma += 128; \
} while (0)

// Fused chamfer, 32x32x16 MFMA. Block = (batch, 256-row i-chunk, 512-col
// j-segment); 4 waves x 64 rows (2 A-frags each, all 64 lanes carry data:
// row=lane&31, K-half=lane>>5). B staged to LDS from raw y; 16 32-col tiles,
// 4-slot rotating ds_read pipeline, queue-simulated waits 3,4,5,6|7x8|7,6,5,4.
__global__ __launch_bounds__(256) void chamfer_mfma(const float* __restrict__ x,
                                                    const float* __restrict__ y,
                                                    float* __restrict__ colpart,
                                                    float* __restrict__ rowpart,
                                                    float* __restrict__ out) {
    constexpr int QLEN = NPTS / JSEG;       // 512 cols = 16 tiles of 32
    __shared__ u16  Bst[QLEN * 16];         // 16 KB
    __shared__ float colmin[QLEN];          // 2 KB

    int bid  = blockIdx.x;                 // [b:16][ic:16][jseg:8]
    int b    = bid >> 7;
    int ic   = (bid >> 3) & 15;
    int jseg = bid & 7;
    int tid  = threadIdx.x;
    int wv   = tid >> 6, lane = tid & 63;
    int lc   = lane & 31;                  // row/col within 32-group
    int hh   = lane >> 5;                  // K-half

    if (bid == 0 && tid == 0) out[0] = 0.0f;

    int i0 = ic * 256 + wv * 64;
    int j0 = jseg * QLEN;

    // stage B: 512 recs, 2 per thread, built from raw y
    {
        const float* ysrc = y + ((size_t)b * NPTS + j0) * 3;
        f4* dst = (f4*)Bst;
        #pragma unroll
        for (int r = 0; r < 2; ++r) {
            int rec = tid * 2 + r;
            float a = ysrc[rec * 3 + 0];
            float bb = ysrc[rec * 3 + 1];
            float c = ysrc[rec * 3 + 2];
            f4 v0, v1;
            build_brec(a, bb, c, &v0, &v1);
            dst[rec * 2 + 0] = v0;
            dst[rec * 2 + 1] = v1;
        }
    }
    for (int i = tid; i < QLEN; i += 256) colmin[i] = 3.4e38f;

    // A frags (2 x 32 rows): lane = row lc, K-half hh
    bh8 af0, af1;
    {
        const float* xsrc = x + ((size_t)b * NPTS + i0 + lc) * 3;
        bh8 h0, h1;
        build_arec(xsrc[0], xsrc[1], xsrc[2], &h0, &h1);
        af0 = hh ? h1 : h0;
        build_arec(xsrc[96], xsrc[97], xsrc[98], &h0, &h1);   // +32 rows
        af1 = hh ? h1 : h0;
    }
    __syncthreads();

    // frag addr: rec (tile*32+lc), half hh; tile stride 1024B
    u32 lofs = (u32)(uintptr_t)&Bst[0] + (u32)(lc * 32 + hh * 16);
    u32 cma  = (u32)(uintptr_t)&colmin[0] + (u32)lc * 4;

    f32x16 zc;
    #pragma unroll
    for (int i = 0; i < 16; ++i) zc[i] = 0.0f;
    f32x16 ra0, ra1;
    #pragma unroll
    for (int i = 0; i < 16; ++i) { ra0[i] = 3.4e38f; ra1[i] = 3.4e38f; }
    f32x16 p, q;
    bh8 s0, s1, s2, s3;

    // prologue: tiles 0..3
    DSRL(s0, lofs, "0");    DSRL(s1, lofs, "1024");
    DSRL(s2, lofs, "2048"); DSRL(s3, lofs, "3072");

    // tiles 0..3 (waits 3,4,5,6), prefetch 4..7
    #define WAITL_CUR(sl) WAITL("3", sl)
    TILE(s0, lofs, "4096");
    #undef WAITL_CUR
    #define WAITL_CUR(sl) WAITL("4", sl)
    TILE(s1, lofs, "5120");
    #undef WAITL_CUR
    #define WAITL_CUR(sl) WAITL("5", sl)
    TILE(s2, lofs, "6144");
    #undef WAITL_CUR
    #define WAITL_CUR(sl) WAITL("6", sl)
    TILE(s3, lofs, "7168");
    #undef WAITL_CUR

    u32 lofs2 = lofs + 8192;               // prefetch base = tile 8
    #define WAITL_CUR(sl) WAITL("7", sl)
    #pragma unroll 1
    for (int k = 0; k < 2; ++k) {          // tiles 4..11, prefetch 8..15
        TILE(s0, lofs2, "0");
        TILE(s1, lofs2, "1024");
        TILE(s2, lofs2, "2048");
        TILE(s3, lofs2, "3072");
        lofs2 += 4096;
    }
    TILED(s0);                             // tile 12, wait 7
    #undef WAITL_CUR
    #define WAITL_CUR(sl) WAITL("6", sl)
    TILED(s1);                             // tile 13
    #undef WAITL_CUR
    #define WAITL_CUR(sl) WAITL("5", sl)
    TILED(s2);                             // tile 14
    #undef WAITL_CUR
    #define WAITL_CUR(sl) WAITL("4", sl)
    TILED(s3);                             // tile 15
    #undef WAITL_CUR

    // rowmin finalize: reduce each reg across the 32 col-lanes of its half
    // (xor masks 1..16 keep bit5), store per-row. Row = (r&3)+8*(r>>2)+4*hh.
    #define RRED32(v) { v = fminf(v, __shfl_xor(v, 1)); v = fminf(v, __shfl_xor(v, 2)); \
                        v = fminf(v, __shfl_xor(v, 4)); v = fminf(v, __shfl_xor(v, 8)); \
                        v = fminf(v, __shfl_xor(v, 16)); }
    float* rowb = rowpart + (size_t)jseg * TOT + (size_t)b * NPTS + i0 + 4 * hh;
    #define RFIN(ra, f, r) do { \
        float v = ra[r]; \
        RRED32(v) \
        if (lc == 0) rowb[f * 32 + ((r) >> 2) * 8 + ((r) & 3)] = v; \
    } while (0)
    #pragma unroll
    for (int r = 0; r < 16; ++r) RFIN(ra0, 0, r);
    #pragma unroll
    for (int r = 0; r < 16; ++r) RFIN(ra1, 1, r);

    __syncthreads();                       // all ds_min retired
    for (int j = tid; j < QLEN; j += 256)
        colpart[(size_t)ic * TOT + (size_t)b * NPTS + j0 + j] = colmin[j];
}

// pass2: fold row partials (8 jseg) + col partials (16 ic), mean both.
__global__ __launch_bounds__(256) void chamfer_pass2(const float* __restrict__ rowpart,
                                                     const float* __restrict__ colpart,
                                                     float* __restrict__ out) {
    int t = blockIdx.x * 256 + threadIdx.x;
    float mr = rowpart[t];
    #pragma unroll
    for (int s = 1; s < JSEG; ++s) mr = fminf(mr, rowpart[(size_t)s * TOT + t]);
    float mc = colpart[t];
    #pragma unroll
    for (int ic = 1; ic < 16; ++ic) mc = fminf(mc, colpart[(size_t)ic * TOT + t]);

    float s = mr + mc;
    #pragma unroll
    for (int off = 32; off; off >>= 1) s += __shfl_down(s, off);
    __shared__ float red[4];
    int lane = threadIdx.x & 63, wid = threadIdx.x >> 6;
    if (lane == 0) red[wid] = s;
    __syncthreads();
    if (threadIdx.x == 0) {
        float tot = (red[0] + red[1]) + (red[2] + red[3]);
        atomicAdd(out, tot * (1.0f / (float)TOT));
    }
}

// ---------------- fallback (no workspace): direct form ----------------
__global__ __launch_bounds__(256) void chamfer_direct(const float* __restrict__ x,
                                                      const float* __restrict__ y,
                                                      float* __restrict__ out) {
    int blk = blockIdx.x;
    int dir = blk >> 8;
    int t = blk & 255;
    int b = t >> 4;
    int chunk = t & 15;
    const float* __restrict__ P = (dir ? y : x) + (b * NPTS + chunk * 256) * 3;
    const float* __restrict__ Q = (dir ? x : y) + b * NPTS * 3;
    float px = P[threadIdx.x * 3 + 0];
    float py = P[threadIdx.x * 3 + 1];
    float pz = P[threadIdx.x * 3 + 2];
    float b0 = 3.4e38f, b1 = 3.4e38f, b2 = 3.4e38f, b3 = 3.4e38f;
    for (int j = 0; j < NPTS; j += 4) {
        #pragma unroll
        for (int u = 0; u < 4; ++u) {
            float dx = px - Q[(j + u) * 3 + 0];
            float dy = py - Q[(j + u) * 3 + 1];
            float dz = pz - Q[(j + u) * 3 + 2];
            float d = fmaf(dx, dx, fmaf(dy, dy, dz * dz));
            if (u == 0) b0 = fminf(b0, d);
            if (u == 1) b1 = fminf(b1, d);
            if (u == 2) b2 = fminf(b2, d);
            if (u == 3) b3 = fminf(b3, d);
        }
    }
    float best = fminf(fminf(b0, b1), fminf(b2, b3));
    float v = best;
    #pragma unroll
    for (int off = 32; off; off >>= 1) v += __shfl_down(v, off);
    __shared__ float red[4];
    int lane = threadIdx.x & 63, wid = threadIdx.x >> 6;
    if (lane == 0) red[wid] = v;
    __syncthreads();
    if (threadIdx.x == 0) {
        float s = (red[0] + red[1]) + (red[2] + red[3]);
        atomicAdd(out, s * (1.0f / (float)TOT));
    }
}

__global__ void zero_kernel(float* out) { out[0] = 0.0f; }

extern "C" void kernel_launch(void* const* d_in, const int* in_sizes, int n_in,
                              void* d_out, int out_size, void* d_ws, size_t ws_size,
                              hipStream_t stream) {
    const float* x = (const float*)d_in[0];
    const float* y = (const float*)d_in[1];
    float* out = (float*)d_out;

    // ws: colpart 4MB (16 ic) | rowpart 2MB (8 jseg)
    size_t need = (size_t)6 << 20;
    if (ws_size >= need) {
        float* colpart = (float*)d_ws;
        float* rowpart = (float*)((char*)d_ws + ((size_t)4 << 20));
        hipLaunchKernelGGL(chamfer_mfma, dim3(16 * 16 * JSEG), dim3(256), 0, stream,
                           x, y, colpart, rowpart, out);
        hipLaunchKernelGGL(chamfer_pass2, dim3(TOT / 256), dim3(256), 0, stream,
                           rowpart, colpart, out);
    } else {
        hipLaunchKernelGGL(zero_kernel, dim3(1), dim3(1), 0, stream, out);
        hipLaunchKernelGGL(chamfer_direct, dim3(512), dim3(256), 0, stream, x, y, out);
    }
}

// Round 22
// 38.824 us; speedup vs baseline: 1.4165x; 1.4165x over previous
//
#include <hip/hip_runtime.h>
#include <stdint.h>

#define BATCH 16
#define NPTS  4096
#define TOT   (BATCH * NPTS)     // 65536 points per tensor
#define JSEG  8

typedef float f4 __attribute__((ext_vector_type(4)));
typedef float f32x4 __attribute__((ext_vector_type(4)));
typedef short bh8 __attribute__((ext_vector_type(8)));   // 8 bf16 = 4 VGPR
typedef uint32_t u32;
typedef unsigned short u16;

__device__ __forceinline__ u16 bfr(float f) {
    union { float f; u32 u; } v; v.f = f;
    u32 r = v.u + 0x7FFF + ((v.u >> 16) & 1);
    return (u16)(r >> 16);
}
__device__ __forceinline__ float bfback(u16 h) {
    union { u32 u; float f; } v; v.u = ((u32)h) << 16; return v.f;
}
#define BF16_ONE ((u16)0x3F80)

#define MIN3r(d, a, b, c) \
    asm("v_min3_f32 %0, %1, %2, %3" : "=v"(d) : "v"(a), "v"(b), "v"(c))

// Record layout (verified R14):
//  A: [ahx,ahy,ahz, ahx,ahy,ahz, alx,aly | alz, x2h,x2l, 1,1, 0,0,0]   (A=-2x)
//  B: [yhx,yhy,yhz, ylx,yly,ylz, yhx,yhy | yhz, 1,1, y2h,y2l, 0,0,0]
// => sum_k A_k*B_k = Ah.Yh + Ah.Yl + Al.Yh + x2 + y2 == D[i,j]

__device__ __forceinline__ void build_arec(float a, float b, float c,
                                           bh8* h0, bh8* h1) {
    float s2 = fmaf(a, a, fmaf(b, b, c * c));
    u16 s2h = bfr(s2);
    u16 s2l = bfr(s2 - bfback(s2h));
    float ax = -2.0f * a, ay = -2.0f * b, az = -2.0f * c;
    u16 ahx = bfr(ax), ahy = bfr(ay), ahz = bfr(az);
    u16 alx = bfr(ax - bfback(ahx));
    u16 aly = bfr(ay - bfback(ahy));
    u16 alz = bfr(az - bfback(ahz));
    union { u16 h[8]; bh8 v; } r0, r1;
    r0.h[0] = ahx; r0.h[1] = ahy; r0.h[2] = ahz;
    r0.h[3] = ahx; r0.h[4] = ahy; r0.h[5] = ahz;
    r0.h[6] = alx; r0.h[7] = aly;
    r1.h[0] = alz; r1.h[1] = s2h; r1.h[2] = s2l;
    r1.h[3] = BF16_ONE; r1.h[4] = BF16_ONE;
    r1.h[5] = 0; r1.h[6] = 0; r1.h[7] = 0;
    *h0 = r0.v; *h1 = r1.v;
}

__device__ __forceinline__ void build_brec(float a, float b, float c,
                                           f4* v0, f4* v1) {
    float s2 = fmaf(a, a, fmaf(b, b, c * c));
    u16 s2h = bfr(s2);
    u16 s2l = bfr(s2 - bfback(s2h));
    u16 yhx = bfr(a), yhy = bfr(b), yhz = bfr(c);
    u16 ylx = bfr(a - bfback(yhx));
    u16 yly = bfr(b - bfback(yhy));
    u16 ylz = bfr(c - bfback(yhz));
    union { u16 h[16]; f4 v[2]; } rec;
    rec.h[0] = yhx;  rec.h[1] = yhy;  rec.h[2] = yhz;
    rec.h[3] = ylx;  rec.h[4] = yly;  rec.h[5] = ylz;
    rec.h[6] = yhx;  rec.h[7] = yhy;
    rec.h[8] = yhz;  rec.h[9] = BF16_ONE; rec.h[10] = BF16_ONE;
    rec.h[11] = s2h; rec.h[12] = s2l;
    rec.h[13] = 0; rec.h[14] = 0; rec.h[15] = 0;
    *v0 = rec.v[0]; *v1 = rec.v[1];
}

// LDS frag read, immediate offset
#define DSRL(dst, base, imm) \
    asm volatile("ds_read_b128 %0, %1 offset:" imm : "=v"(dst) : "v"(base))

// counted lgkm wait (queue-simulated counts incl. interleaved ds_min)
#define WAITL(cnt, slot) do { \
    asm volatile("s_waitcnt lgkmcnt(" cnt ")" : "+v"(slot)); \
    __builtin_amdgcn_sched_barrier(0); \
} while (0)

// 8 MFMAs: 128 rows x 16 cols per B-frag read
#define MF8(BB) do { \
    p0 = __builtin_amdgcn_mfma_f32_16x16x32_bf16(af0, BB, zc, 0, 0, 0); \
    p1 = __builtin_amdgcn_mfma_f32_16x16x32_bf16(af1, BB, zc, 0, 0, 0); \
    p2 = __builtin_amdgcn_mfma_f32_16x16x32_bf16(af2, BB, zc, 0, 0, 0); \
    p3 = __builtin_amdgcn_mfma_f32_16x16x32_bf16(af3, BB, zc, 0, 0, 0); \
    p4 = __builtin_amdgcn_mfma_f32_16x16x32_bf16(af4, BB, zc, 0, 0, 0); \
    p5 = __builtin_amdgcn_mfma_f32_16x16x32_bf16(af5, BB, zc, 0, 0, 0); \
    p6 = __builtin_amdgcn_mfma_f32_16x16x32_bf16(af6, BB, zc, 0, 0, 0); \
    p7 = __builtin_amdgcn_mfma_f32_16x16x32_bf16(af7, BB, zc, 0, 0, 0); \
} while (0)

// per-tile epilogue: 32 rowmin folds + colmin tree over 32 values + 1 ds_min
#define EPI1() do { \
    ra0[0]=fminf(ra0[0],p0[0]); ra0[1]=fminf(ra0[1],p0[1]); ra0[2]=fminf(ra0[2],p0[2]); ra0[3]=fminf(ra0[3],p0[3]); \
    ra1[0]=fminf(ra1[0],p1[0]); ra1[1]=fminf(ra1[1],p1[1]); ra1[2]=fminf(ra1[2],p1[2]); ra1[3]=fminf(ra1[3],p1[3]); \
    ra2[0]=fminf(ra2[0],p2[0]); ra2[1]=fminf(ra2[1],p2[1]); ra2[2]=fminf(ra2[2],p2[2]); ra2[3]=fminf(ra2[3],p2[3]); \
    ra3[0]=fminf(ra3[0],p3[0]); ra3[1]=fminf(ra3[1],p3[1]); ra3[2]=fminf(ra3[2],p3[2]); ra3[3]=fminf(ra3[3],p3[3]); \
    ra4[0]=fminf(ra4[0],p4[0]); ra4[1]=fminf(ra4[1],p4[1]); ra4[2]=fminf(ra4[2],p4[2]); ra4[3]=fminf(ra4[3],p4[3]); \
    ra5[0]=fminf(ra5[0],p5[0]); ra5[1]=fminf(ra5[1],p5[1]); ra5[2]=fminf(ra5[2],p5[2]); ra5[3]=fminf(ra5[3],p5[3]); \
    ra6[0]=fminf(ra6[0],p6[0]); ra6[1]=fminf(ra6[1],p6[1]); ra6[2]=fminf(ra6[2],p6[2]); ra6[3]=fminf(ra6[3],p6[3]); \
    ra7[0]=fminf(ra7[0],p7[0]); ra7[1]=fminf(ra7[1],p7[1]); ra7[2]=fminf(ra7[2],p7[2]); ra7[3]=fminf(ra7[3],p7[3]); \
    float t0,t1,t2,t3,t4,t5,t6,t7,t8,t9,t10,u0,u1,u2,u3,cv; \
    MIN3r(t0, p0[0], p0[1], p0[2]); \
    MIN3r(t1, p0[3], p1[0], p1[1]); \
    MIN3r(t2, p1[2], p1[3], p2[0]); \
    MIN3r(t3, p2[1], p2[2], p2[3]); \
    MIN3r(t4, p3[0], p3[1], p3[2]); \
    MIN3r(t5, p3[3], p4[0], p4[1]); \
    MIN3r(t6, p4[2], p4[3], p5[0]); \
    MIN3r(t7, p5[1], p5[2], p5[3]); \
    MIN3r(t8, p6[0], p6[1], p6[2]); \
    MIN3r(t9, p6[3], p7[0], p7[1]); \
    MIN3r(t10, p7[2], p7[3], t0); \
    MIN3r(u0, t1, t2, t3); \
    MIN3r(u1, t4, t5, t6); \
    MIN3r(u2, t7, t8, t9); \
    MIN3r(u3, t10, u0, u1); \
    cv = fminf(u2, u3); \
    asm volatile("ds_min_f32 %0, %1" :: "v"(cma), "v"(cv)); \
    cma += 64; \
} while (0)

// Fused: block = (batch, 512-row i-chunk, 512-col j-segment); builds its own
// A-frags (registers) and B-records (LDS) from raw x/y - no pack kernel.
// 4-slot rotating ds_read pipeline, queue-simulated counted lgkmcnt waits.
// (R20 configuration - best verified: 39.1 us total.)
__global__ __launch_bounds__(256) void chamfer_mfma(const float* __restrict__ x,
                                                    const float* __restrict__ y,
                                                    float* __restrict__ colpart,
                                                    float* __restrict__ rowpart,
                                                    float* __restrict__ out) {
    constexpr int QLEN = NPTS / JSEG;       // 512 cols
    __shared__ u16  Bst[QLEN * 16];         // 16 KB
    __shared__ float colmin[QLEN];          // 2 KB

    int bid  = blockIdx.x;                 // [b:16][ic:8][jseg:8]
    int b    = bid >> 6;
    int ic   = (bid >> 3) & 7;
    int jseg = bid & 7;
    int tid  = threadIdx.x;
    int wv   = tid >> 6, lane = tid & 63;
    int lg   = lane >> 4, lm = lane & 15;

    if (bid == 0 && tid == 0) out[0] = 0.0f;   // stream-ordered before pass2

    int i0 = ic * 512 + wv * 128;
    int j0 = jseg * QLEN;

    // stage B segment: 2 records per thread, built from raw y
    {
        const float* ysrc = y + ((size_t)b * NPTS + j0) * 3;
        f4* dst = (f4*)Bst;
        #pragma unroll
        for (int r = 0; r < 2; ++r) {
            int rec = tid * 2 + r;
            float a = ysrc[rec * 3 + 0];
            float bb = ysrc[rec * 3 + 1];
            float c = ysrc[rec * 3 + 2];
            f4 v0, v1;
            build_brec(a, bb, c, &v0, &v1);
            dst[rec * 2 + 0] = v0;
            dst[rec * 2 + 1] = v1;
        }
    }
    for (int i = tid; i < QLEN; i += 256) colmin[i] = 3.4e38f;

    // A frags (8 x 16 rows) built in registers from raw x. Thread (lm,lg)
    // owns row i0+lm+f*16; af = half lg of that row's record (lg>=2 -> 0).
    bh8 af0, af1, af2, af3, af4, af5, af6, af7;
    {
        bh8 z8 = {0, 0, 0, 0, 0, 0, 0, 0};
        const float* xsrc = x + ((size_t)b * NPTS + i0 + lm) * 3;
        #define BUILD_AF(af, f) do { \
            float a = xsrc[f * 48 + 0]; \
            float bb = xsrc[f * 48 + 1]; \
            float c = xsrc[f * 48 + 2]; \
            bh8 h0, h1; \
            build_arec(a, bb, c, &h0, &h1); \
            af = (lg == 0) ? h0 : ((lg == 1) ? h1 : z8); \
        } while (0)
        BUILD_AF(af0, 0); BUILD_AF(af1, 1); BUILD_AF(af2, 2); BUILD_AF(af3, 3);
        BUILD_AF(af4, 4); BUILD_AF(af5, 5); BUILD_AF(af6, 6); BUILD_AF(af7, 7);
        #undef BUILD_AF
    }
    __syncthreads();                       // staging + colmin init complete

    u32 lofs = (u32)(uintptr_t)&Bst[0] + ((lg < 2) ? (u32)(lm * 32 + lg * 16) : 0u);
    u32 cma  = (u32)(uintptr_t)&colmin[0] + (u32)lm * 4;

    f32x4 zc = {0.f, 0.f, 0.f, 0.f};
    f32x4 big = {3.4e38f, 3.4e38f, 3.4e38f, 3.4e38f};
    f32x4 ra0 = big, ra1 = big, ra2 = big, ra3 = big;
    f32x4 ra4 = big, ra5 = big, ra6 = big, ra7 = big;
    f32x4 p0, p1, p2, p3, p4, p5, p6, p7;
    bh8 s0, s1, s2, s3;

    // prologue: tiles 0..3 (tile stride 512B)
    DSRL(s0, lofs, "0");    DSRL(s1, lofs, "512");
    DSRL(s2, lofs, "1024"); DSRL(s3, lofs, "1536");

    // tiles 0..3 (waits 3,4,5,6), prefetch tiles 4..7
    WAITL("3", s0); MF8(s0); DSRL(s0, lofs, "2048"); EPI1();
    WAITL("4", s1); MF8(s1); DSRL(s1, lofs, "2560"); EPI1();
    WAITL("5", s2); MF8(s2); DSRL(s2, lofs, "3072"); EPI1();
    WAITL("6", s3); MF8(s3); DSRL(s3, lofs, "3584"); EPI1();

    u32 lofs2 = lofs + 4096;               // prefetch base = tile 8
    #pragma unroll 1
    for (int k = 0; k < 6; ++k) {          // tiles 4..27, prefetch 8..31
        WAITL("7", s0); MF8(s0); DSRL(s0, lofs2, "0");    EPI1();
        WAITL("7", s1); MF8(s1); DSRL(s1, lofs2, "512");  EPI1();
        WAITL("7", s2); MF8(s2); DSRL(s2, lofs2, "1024"); EPI1();
        WAITL("7", s3); MF8(s3); DSRL(s3, lofs2, "1536"); EPI1();
        lofs2 += 2048;
    }
    // drain: tiles 28..31 (waits 7,6,5,4)
    WAITL("7", s0); MF8(s0); EPI1();
    WAITL("6", s1); MF8(s1); EPI1();
    WAITL("5", s2); MF8(s2); EPI1();
    WAITL("4", s3); MF8(s3); EPI1();

    // rowmin finalize: reduce across 16 col-lanes, write per-row values
    #define RRED(r) { r = fminf(r, __shfl_xor(r, 1)); r = fminf(r, __shfl_xor(r, 2)); \
                      r = fminf(r, __shfl_xor(r, 4)); r = fminf(r, __shfl_xor(r, 8)); }
    float* rp = rowpart + (size_t)jseg * TOT + (size_t)b * NPTS + i0 + lg * 4;
    #define RSTORE(pf, fi) do { \
        float a = pf[0], bq = pf[1], c = pf[2], d = pf[3]; \
        RRED(a) RRED(bq) RRED(c) RRED(d) \
        if (lm == 0) { rp[fi*16 + 0] = a; rp[fi*16 + 1] = bq; \
                       rp[fi*16 + 2] = c; rp[fi*16 + 3] = d; } \
    } while (0)
    RSTORE(ra0, 0); RSTORE(ra1, 1); RSTORE(ra2, 2); RSTORE(ra3, 3);
    RSTORE(ra4, 4); RSTORE(ra5, 5); RSTORE(ra6, 6); RSTORE(ra7, 7);

    __syncthreads();                       // all ds_min retired
    for (int j = tid; j < QLEN; j += 256)
        colpart[(size_t)ic * TOT + (size_t)b * NPTS + j0 + j] = colmin[j];
}

// pass2: fold row partials (8 jseg) + col partials (8 ic), mean both.
__global__ __launch_bounds__(256) void chamfer_pass2(const float* __restrict__ rowpart,
                                                     const float* __restrict__ colpart,
                                                     float* __restrict__ out) {
    int t = blockIdx.x * 256 + threadIdx.x;
    float mr = rowpart[t];
    #pragma unroll
    for (int s = 1; s < JSEG; ++s) mr = fminf(mr, rowpart[(size_t)s * TOT + t]);
    float mc = colpart[t];
    #pragma unroll
    for (int ic = 1; ic < 8; ++ic) mc = fminf(mc, colpart[(size_t)ic * TOT + t]);

    float s = mr + mc;
    #pragma unroll
    for (int off = 32; off; off >>= 1) s += __shfl_down(s, off);
    __shared__ float red[4];
    int lane = threadIdx.x & 63, wid = threadIdx.x >> 6;
    if (lane == 0) red[wid] = s;
    __syncthreads();
    if (threadIdx.x == 0) {
        float tot = (red[0] + red[1]) + (red[2] + red[3]);
        atomicAdd(out, tot * (1.0f / (float)TOT));
    }
}

// ---------------- fallback (no workspace): direct form ----------------
__global__ __launch_bounds__(256) void chamfer_direct(const float* __restrict__ x,
                                                      const float* __restrict__ y,
                                                      float* __restrict__ out) {
    int blk = blockIdx.x;
    int dir = blk >> 8;
    int t = blk & 255;
    int b = t >> 4;
    int chunk = t & 15;
    const float* __restrict__ P = (dir ? y : x) + (b * NPTS + chunk * 256) * 3;
    const float* __restrict__ Q = (dir ? x : y) + b * NPTS * 3;
    float px = P[threadIdx.x * 3 + 0];
    float py = P[threadIdx.x * 3 + 1];
    float pz = P[threadIdx.x * 3 + 2];
    float b0 = 3.4e38f, b1 = 3.4e38f, b2 = 3.4e38f, b3 = 3.4e38f;
    for (int j = 0; j < NPTS; j += 4) {
        #pragma unroll
        for (int u = 0; u < 4; ++u) {
            float dx = px - Q[(j + u) * 3 + 0];
            float dy = py - Q[(j + u) * 3 + 1];
            float dz = pz - Q[(j + u) * 3 + 2];
            float d = fmaf(dx, dx, fmaf(dy, dy, dz * dz));
            if (u == 0) b0 = fminf(b0, d);
            if (u == 1) b1 = fminf(b1, d);
            if (u == 2) b2 = fminf(b2, d);
            if (u == 3) b3 = fminf(b3, d);
        }
    }
    float best = fminf(fminf(b0, b1), fminf(b2, b3));
    float v = best;
    #pragma unroll
    for (int off = 32; off; off >>= 1) v += __shfl_down(v, off);
    __shared__ float red[4];
    int lane = threadIdx.x & 63, wid = threadIdx.x >> 6;
    if (lane == 0) red[wid] = v;
    __syncthreads();
    if (threadIdx.x == 0) {
        float s = (red[0] + red[1]) + (red[2] + red[3]);
        atomicAdd(out, s * (1.0f / (float)TOT));
    }
}

__global__ void zero_kernel(float* out) { out[0] = 0.0f; }

extern "C" void kernel_launch(void* const* d_in, const int* in_sizes, int n_in,
                              void* d_out, int out_size, void* d_ws, size_t ws_size,
                              hipStream_t stream) {
    const float* x = (const float*)d_in[0];
    const float* y = (const float*)d_in[1];
    float* out = (float*)d_out;

    // ws: colpart 2MB | rowpart 2MB
    size_t need = (size_t)4 << 20;
    if (ws_size >= need) {
        float* colpart = (float*)d_ws;
        float* rowpart = (float*)((char*)d_ws + ((size_t)2 << 20));
        hipLaunchKernelGGL(chamfer_mfma, dim3(16 * 8 * JSEG), dim3(256), 0, stream,
                           x, y, colpart, rowpart, out);
        hipLaunchKernelGGL(chamfer_pass2, dim3(TOT / 256), dim3(256), 0, stream,
                           rowpart, colpart, out);
    } else {
        hipLaunchKernelGGL(zero_kernel, dim3(1), dim3(1), 0, stream, out);
        hipLaunchKernelGGL(chamfer_direct, dim3(512), dim3(256), 0, stream, x, y, out);
    }
}